// Round 1
// baseline (5400.942 us; speedup 1.0000x reference)
//
#include <hip/hip_runtime.h>
#include <hip/hip_bf16.h>

// Problem constants
#define BB 16
#define SS 1024
#define DD 1024
#define EE 1024
#define TWOE 2048
#define TWOS 2048

#define TILE 64
#define TK 16

// ---------------------------------------------------------------------------
// Generic tiled fp32 GEMM.
//   C[m,n] (+)= alpha * sum_k A[m,k] * B'[n,k]  (+ bias[n]) (+ addc)
//   BT=true : B is (N,K) row-major   (C = A * B^T)   "NT"
//   BT=false: B is (K,N) row-major   (C = A * B)     "NN"
// All of M,N divisible by 64, K divisible by 16, lda/ldb/ldc divisible by 4.
// alpha_ptr/addc_ptr are device pointers (may be null -> 1.0 / 0.0).
// ---------------------------------------------------------------------------
template <bool BT>
__global__ __launch_bounds__(256) void gemm_kernel(
    const float* __restrict__ A, long sAb, int lda,
    const float* __restrict__ Bm, long sBb, int ldb,
    float* __restrict__ C, long sCb, int ldc,
    int M, int N, int K,
    const float* __restrict__ bias,
    const float* __restrict__ alpha_ptr, int alpha_idx,
    const float* __restrict__ addc_ptr,
    int accumulate)
{
    __shared__ __align__(16) float As[TK][TILE];
    __shared__ __align__(16) float Bs[TK][TILE];

    const int tid = threadIdx.x;
    const int tx = tid & 15, ty = tid >> 4;
    const int m0 = blockIdx.y * TILE, n0 = blockIdx.x * TILE;

    const float* Ab = A + (long)blockIdx.z * sAb;
    const float* Bb = Bm + (long)blockIdx.z * sBb;
    float* Cb = C + (long)blockIdx.z * sCb;

    const int lrow = tid >> 2;        // 0..63
    const int lk   = (tid & 3) << 2;  // 0,4,8,12
    const int bkk  = tid >> 4;        // 0..15  (NN b-load)
    const int bnn  = (tid & 15) << 2; // 0..60  (NN b-load)

    float acc[4][4] = {};

    for (int k0 = 0; k0 < K; k0 += TK) {
        float4 a4 = *(const float4*)(Ab + (long)(m0 + lrow) * lda + k0 + lk);
        float4 b4;
        if (BT) b4 = *(const float4*)(Bb + (long)(n0 + lrow) * ldb + k0 + lk);
        else    b4 = *(const float4*)(Bb + (long)(k0 + bkk) * ldb + n0 + bnn);

        __syncthreads();
        As[lk + 0][lrow] = a4.x;
        As[lk + 1][lrow] = a4.y;
        As[lk + 2][lrow] = a4.z;
        As[lk + 3][lrow] = a4.w;
        if (BT) {
            Bs[lk + 0][lrow] = b4.x;
            Bs[lk + 1][lrow] = b4.y;
            Bs[lk + 2][lrow] = b4.z;
            Bs[lk + 3][lrow] = b4.w;
        } else {
            *(float4*)&Bs[bkk][bnn] = b4;
        }
        __syncthreads();

#pragma unroll
        for (int kk = 0; kk < TK; ++kk) {
            float4 av = *(const float4*)&As[kk][ty << 2];
            float4 bv = *(const float4*)&Bs[kk][tx << 2];
            float a[4] = {av.x, av.y, av.z, av.w};
            float b[4] = {bv.x, bv.y, bv.z, bv.w};
#pragma unroll
            for (int i = 0; i < 4; ++i)
#pragma unroll
                for (int j = 0; j < 4; ++j)
                    acc[i][j] = fmaf(a[i], b[j], acc[i][j]);
        }
    }

    const float alpha = alpha_ptr ? alpha_ptr[alpha_idx] : 1.0f;
    const float addc  = addc_ptr ? addc_ptr[0] : 0.0f;

#pragma unroll
    for (int i = 0; i < 4; ++i) {
        int r = m0 + (ty << 2) + i;
        float* crow = Cb + (long)r * ldc + n0 + (tx << 2);
        float vals[4];
#pragma unroll
        for (int j = 0; j < 4; ++j) {
            float v = alpha * acc[i][j] + addc;
            if (bias) v += bias[n0 + (tx << 2) + j];
            vals[j] = v;
        }
        if (accumulate) {
            float4 old = *(const float4*)crow;
            vals[0] += old.x; vals[1] += old.y; vals[2] += old.z; vals[3] += old.w;
        }
        float4 o;
        o.x = vals[0]; o.y = vals[1]; o.z = vals[2]; o.w = vals[3];
        *(float4*)crow = o;
    }
}

// ---------------------------------------------------------------------------
// Block reductions (256 threads = 4 waves of 64)
// ---------------------------------------------------------------------------
__device__ inline float blockReduceSum(float v, float* red)
{
#pragma unroll
    for (int off = 32; off > 0; off >>= 1) v += __shfl_xor(v, off, 64);
    __syncthreads();
    if ((threadIdx.x & 63) == 0) red[threadIdx.x >> 6] = v;
    __syncthreads();
    return red[0] + red[1] + red[2] + red[3];
}

__device__ inline float blockReduceMax(float v, float* red)
{
#pragma unroll
    for (int off = 32; off > 0; off >>= 1) v = fmaxf(v, __shfl_xor(v, off, 64));
    __syncthreads();
    if ((threadIdx.x & 63) == 0) red[threadIdx.x >> 6] = v;
    __syncthreads();
    return fmaxf(fmaxf(red[0], red[1]), fmaxf(red[2], red[3]));
}

// ---------------------------------------------------------------------------
// L2-normalize each half-row (length 1024) of ctx (rows of length 2048).
// grid.x = nrows*2, block 256.
// ---------------------------------------------------------------------------
__global__ __launch_bounds__(256) void l2norm_kernel(float* __restrict__ ctx)
{
    __shared__ float red[4];
    const long row = blockIdx.x >> 1;
    const int half = blockIdx.x & 1;
    float* p = ctx + row * TWOS + half * SS;
    const int t = threadIdx.x;

    float v[4];
    float ss = 0.0f;
#pragma unroll
    for (int i = 0; i < 4; ++i) {
        v[i] = p[t + 256 * i];
        ss = fmaf(v[i], v[i], ss);
    }
    ss = blockReduceSum(ss, red);
    const float inv = 1.0f / fmaxf(sqrtf(ss), 1e-12f);
#pragma unroll
    for (int i = 0; i < 4; ++i) p[t + 256 * i] = v[i] * inv;
}

// ---------------------------------------------------------------------------
// Row-wise: softmax -> mask -> L1 renormalize.  Row length 1024.
// grid.x = nrows, block 256.
// ---------------------------------------------------------------------------
__global__ __launch_bounds__(256) void softmax_mask_kernel(
    float* __restrict__ attn, const int* __restrict__ mask)
{
    __shared__ float red[4];
    const long row = blockIdx.x;
    float* p = attn + row * SS;
    const int* mrow = mask + row * SS;
    const int t = threadIdx.x;

    float v[4];
    int mv[4];
#pragma unroll
    for (int i = 0; i < 4; ++i) {
        v[i] = p[t + 256 * i];
        mv[i] = mrow[t + 256 * i];
    }
    float mx = fmaxf(fmaxf(v[0], v[1]), fmaxf(v[2], v[3]));
    mx = blockReduceMax(mx, red);

    float e[4];
    float s = 0.0f;
#pragma unroll
    for (int i = 0; i < 4; ++i) {
        e[i] = expf(v[i] - mx);
        s += e[i];
    }
    s = blockReduceSum(s, red);

    float l1 = 0.0f;
#pragma unroll
    for (int i = 0; i < 4; ++i) {
        e[i] = mv[i] ? e[i] / s : 0.0f;
        l1 += e[i];
    }
    l1 = blockReduceSum(l1, red);
    const float inv = 1.0f / fmaxf(l1, 1e-12f);
#pragma unroll
    for (int i = 0; i < 4; ++i) p[t + 256 * i] = e[i] * inv;
}

// ---------------------------------------------------------------------------
extern "C" void kernel_launch(void* const* d_in, const int* in_sizes, int n_in,
                              void* d_out, int out_size, void* d_ws, size_t ws_size,
                              hipStream_t stream)
{
    const float* x    = (const float*)d_in[0];
    const int*   mask = (const int*)d_in[1];
    const float* Wqkv = (const float*)d_in[2];
    const float* bqkv = (const float*)d_in[3];
    const float* Wctx = (const float*)d_in[4];
    const float* bctx = (const float*)d_in[5];
    const float* Wf   = (const float*)d_in[6];
    const float* bf   = (const float*)d_in[7];
    const float* Wo   = (const float*)d_in[8];
    const float* bo   = (const float*)d_in[9];
    float* out = (float*)d_out;
    float* ws  = (float*)d_ws;

    const long SD  = (long)SS * DD;        // 1M floats per batch of x
    const long Q2  = (long)SS * TWOE;      // 2M floats (qkv / Y / ctx per batch)
    const long AT  = (long)SS * SS;        // 1M floats (attn per batch)

    // Chunk over batches: per-chunk ws = G * (2M + 1M + 2M) floats = 20*G MB
    int G = 16;
    while (G > 1 && (size_t)G * 5 * 1024 * 1024 * sizeof(float) > ws_size) G >>= 1;

    const dim3 blk(256);

    for (int bc0 = 0; bc0 < BB; bc0 += G) {
        float* bufP    = ws;                              // G * 2M floats (qkv / Y / values)
        float* bufAttn = ws + (size_t)G * Q2;             // G * 1M floats
        float* bufCtx  = ws + (size_t)G * (Q2 + AT);      // G * 2M floats
        const float* xb = x + (long)bc0 * SD;

        // 1. qkv = x * Wqkv^T + bqkv           (M=1024, N=2048, K=1024)
        gemm_kernel<true><<<dim3(TWOE / TILE, SS / TILE, G), blk, 0, stream>>>(
            xb, SD, DD, Wqkv, 0, DD, bufP, Q2, TWOE,
            SS, TWOE, DD, bqkv, nullptr, 0, nullptr, 0);

        // 2. attn = Wf[0] * q k^T + bf          (M=N=1024, K=1024)
        gemm_kernel<true><<<dim3(SS / TILE, SS / TILE, G), blk, 0, stream>>>(
            bufP, Q2, TWOE, bufP + EE, Q2, TWOE, bufAttn, AT, SS,
            SS, SS, EE, nullptr, Wf, 0, bf, 0);

        // 3. Y = Wctx * x                       (M=2048, N=1024, K=1024) — overwrites qkv
        gemm_kernel<false><<<dim3(DD / TILE, TWOS / TILE, G), blk, 0, stream>>>(
            Wctx, 0, SS, xb, SD, DD, bufP, Q2, DD,
            TWOS, DD, SS, nullptr, nullptr, 0, nullptr, 0);

        // 4. ctx = x * Y^T + bctx               (M=1024, N=2048, K=1024)
        gemm_kernel<true><<<dim3(TWOS / TILE, SS / TILE, G), blk, 0, stream>>>(
            xb, SD, DD, bufP, Q2, DD, bufCtx, Q2, TWOS,
            SS, TWOS, DD, bctx, nullptr, 0, nullptr, 0);

        // 5. L2-normalize ctx halves
        l2norm_kernel<<<dim3(G * SS * 2), blk, 0, stream>>>(bufCtx);

        // 6. attn += Wf[1] * ctx_q ctx_k^T
        gemm_kernel<true><<<dim3(SS / TILE, SS / TILE, G), blk, 0, stream>>>(
            bufCtx, Q2, TWOS, bufCtx + SS, Q2, TWOS, bufAttn, AT, SS,
            SS, SS, SS, nullptr, Wf, 1, nullptr, 1);

        // 7. softmax -> mask -> L1 renorm
        softmax_mask_kernel<<<dim3(G * SS), blk, 0, stream>>>(
            bufAttn, mask + (long)bc0 * SS * SS);

        // 8. values = attn * x                  (M=1024, N=1024, K=1024) — into bufP
        gemm_kernel<false><<<dim3(DD / TILE, SS / TILE, G), blk, 0, stream>>>(
            bufAttn, AT, SS, xb, SD, DD, bufP, SD, DD,
            SS, DD, SS, nullptr, nullptr, 0, nullptr, 0);

        // 9. o = x * Wo[:, :D]^T + bo
        gemm_kernel<true><<<dim3(DD / TILE, SS / TILE, G), blk, 0, stream>>>(
            xb, SD, DD, Wo, 0, 2 * DD, out + (long)bc0 * SD, SD, DD,
            SS, DD, DD, bo, nullptr, 0, nullptr, 0);

        // 10. o += values * Wo[:, D:]^T
        gemm_kernel<true><<<dim3(DD / TILE, SS / TILE, G), blk, 0, stream>>>(
            bufP, SD, DD, Wo + DD, 0, 2 * DD, out + (long)bc0 * SD, SD, DD,
            SS, DD, DD, nullptr, nullptr, 0, nullptr, 1);
    }
}

// Round 3
// 1862.073 us; speedup vs baseline: 2.9005x; 2.9005x over previous
//
#include <hip/hip_runtime.h>
#include <hip/hip_bf16.h>

// Problem constants
#define BB 16
#define SS 1024
#define DD 1024
#define EE 1024

typedef __hip_bfloat16 bf;
using s8v  = __attribute__((ext_vector_type(8))) short;
using f32x4 = __attribute__((ext_vector_type(4))) float;

// ---------------------------------------------------------------------------
// bf16 NT GEMM with MFMA 16x16x32.
//   C[m,n] (+)= alpha * sum_k A[m,k]*B[n,k]  (+ bias[n]) (+ addc)
// A: (M,K) row-major bf16, B: (N,K) row-major bf16. M,N % 128 == 0, K % 32 == 0.
// Block 256 = 4 waves (2x2), 128x128 tile, each wave 64x64 = 4x4 MFMA tiles.
// OUT_BF16: write Cb (bf16) instead of C (fp32). accumulate only with fp32 out.
// ---------------------------------------------------------------------------
template <bool OUT_BF16>
__global__ __launch_bounds__(256) void gemm_bf16_nt(
    const bf* __restrict__ A, long sA, int lda,
    const bf* __restrict__ B, long sB, int ldb,
    float* __restrict__ C, bf* __restrict__ Cb, long sC, int ldc,
    int K,
    const float* __restrict__ bias,
    const float* __restrict__ alpha_ptr, int alpha_idx,
    const float* __restrict__ addc_ptr,
    int accumulate)
{
    // LDS pitch 40 bf16 (80 B).
    __shared__ __align__(16) unsigned short As[128][40];
    __shared__ __align__(16) unsigned short Bs[128][40];

    const int tid  = threadIdx.x;
    const int wave = tid >> 6, lane = tid & 63;
    const int wm = (wave >> 1) * 64, wn = (wave & 1) * 64;
    const int lm = lane & 15, quad = lane >> 4;

    const int m0 = blockIdx.y * 128, n0 = blockIdx.x * 128;
    const bf* Ab = A + (long)blockIdx.z * sA;
    const bf* Bb = B + (long)blockIdx.z * sB;

    // Staging: 128 rows x 32 cols = 512 s8v(16B) chunks per matrix.
    // chunk c = tid + 256*p: row = c>>2 (0..127), col = (c&3)*8 (0,8,16,24).
    const int r0 = tid >> 2;             // p=0 row
    const int r1 = (tid + 256) >> 2;     // p=1 row
    const int c0c = (tid & 3) << 3;      // col (same for both p since 256%4==0)

    f32x4 acc[4][4];
#pragma unroll
    for (int i = 0; i < 4; ++i)
#pragma unroll
        for (int j = 0; j < 4; ++j)
            acc[i][j] = (f32x4){0.f, 0.f, 0.f, 0.f};

    for (int k0 = 0; k0 < K; k0 += 32) {
        const s8v av0 = *(const s8v*)(Ab + (long)(m0 + r0) * lda + k0 + c0c);
        const s8v av1 = *(const s8v*)(Ab + (long)(m0 + r1) * lda + k0 + c0c);
        const s8v bv0 = *(const s8v*)(Bb + (long)(n0 + r0) * ldb + k0 + c0c);
        const s8v bv1 = *(const s8v*)(Bb + (long)(n0 + r1) * ldb + k0 + c0c);

        __syncthreads();
        *(s8v*)&As[r0][c0c] = av0;
        *(s8v*)&As[r1][c0c] = av1;
        *(s8v*)&Bs[r0][c0c] = bv0;
        *(s8v*)&Bs[r1][c0c] = bv1;
        __syncthreads();

        s8v a[4], b[4];
#pragma unroll
        for (int i = 0; i < 4; ++i) a[i] = *(const s8v*)&As[wm + 16 * i + lm][quad * 8];
#pragma unroll
        for (int j = 0; j < 4; ++j) b[j] = *(const s8v*)&Bs[wn + 16 * j + lm][quad * 8];
#pragma unroll
        for (int i = 0; i < 4; ++i)
#pragma unroll
            for (int j = 0; j < 4; ++j)
                acc[i][j] = __builtin_amdgcn_mfma_f32_16x16x32_bf16(a[i], b[j], acc[i][j], 0, 0, 0);
    }

    const float alpha = alpha_ptr ? alpha_ptr[alpha_idx] : 1.0f;
    const float addc  = addc_ptr ? addc_ptr[0] : 0.0f;
    float* Cp = C ? C + (long)blockIdx.z * sC : nullptr;
    bf* Cbp = OUT_BF16 ? Cb + (long)blockIdx.z * sC : nullptr;

#pragma unroll
    for (int i = 0; i < 4; ++i) {
#pragma unroll
        for (int j = 0; j < 4; ++j) {
            const int cidx = n0 + wn + 16 * j + lm;
            const float bv = bias ? bias[cidx] : 0.0f;
            const long rbase = m0 + wm + 16 * i + quad * 4;
#pragma unroll
            for (int r = 0; r < 4; ++r) {
                float v = alpha * acc[i][j][r] + addc + bv;
                const long off = (rbase + r) * (long)ldc + cidx;
                if (OUT_BF16) {
                    Cbp[off] = __float2bfloat16(v);
                } else {
                    if (accumulate) v += Cp[off];
                    Cp[off] = v;
                }
            }
        }
    }
}

// ---------------------------------------------------------------------------
// Block reductions (256 threads = 4 waves of 64)
// ---------------------------------------------------------------------------
__device__ inline float blockReduceSum(float v, float* red)
{
#pragma unroll
    for (int off = 32; off > 0; off >>= 1) v += __shfl_xor(v, off, 64);
    __syncthreads();
    if ((threadIdx.x & 63) == 0) red[threadIdx.x >> 6] = v;
    __syncthreads();
    return red[0] + red[1] + red[2] + red[3];
}

__device__ inline float blockReduceMax(float v, float* red)
{
#pragma unroll
    for (int off = 32; off > 0; off >>= 1) v = fmaxf(v, __shfl_xor(v, off, 64));
    __syncthreads();
    if ((threadIdx.x & 63) == 0) red[threadIdx.x >> 6] = v;
    __syncthreads();
    return fmaxf(fmaxf(red[0], red[1]), fmaxf(red[2], red[3]));
}

__device__ inline void split_bf16(float v, bf& hi, bf& lo)
{
    hi = __float2bfloat16(v);
    lo = __float2bfloat16(v - __bfloat162float(hi));
}

// ---------------------------------------------------------------------------
// Weight conversions (once per launch)
// ---------------------------------------------------------------------------
// src (rows x src_ld fp32, take cols columns) -> dst rows x 3*cols, B-form [hi,lo,hi]
__global__ __launch_bounds__(256) void split3B_kernel(
    const float* __restrict__ src, bf* __restrict__ dst, int cols, int src_ld, long n)
{
    long i = (long)blockIdx.x * 256 + threadIdx.x;
    if (i >= n) return;
    long r = i / cols; int c = (int)(i % cols);
    bf hi, lo; split_bf16(src[r * src_ld + c], hi, lo);
    bf* d = dst + (r * cols + c) * 3;
    d[0] = hi; d[1] = lo; d[2] = hi;
}

// plain fp32 -> bf16 with source stride
__global__ __launch_bounds__(256) void conv_kernel(
    const float* __restrict__ src, bf* __restrict__ dst, int cols, int src_ld, long n)
{
    long i = (long)blockIdx.x * 256 + threadIdx.x;
    if (i >= n) return;
    long r = i / cols; int c = (int)(i % cols);
    dst[i] = __float2bfloat16(src[r * src_ld + c]);
}

// ---------------------------------------------------------------------------
// x -> x3 (A-form split3, S x 3D), x1 (bf16 S x D), xT1 (bf16 D x S)
// grid (D/32, S/32, G), block 256
// ---------------------------------------------------------------------------
__global__ __launch_bounds__(256) void conv_x_kernel(
    const float* __restrict__ x, bf* __restrict__ x3,
    bf* __restrict__ x1, bf* __restrict__ xT1)
{
    __shared__ float t[32][33];
    const int b = blockIdx.z;
    const int c0 = blockIdx.x * 32, r0 = blockIdx.y * 32;
    const int tx = threadIdx.x & 31, ty = threadIdx.x >> 5;  // ty 0..7
    const float* xb = x + (long)b * SS * DD;
#pragma unroll
    for (int p = 0; p < 4; ++p) {
        const int r = ty + 8 * p;
        const float v = xb[(long)(r0 + r) * DD + c0 + tx];
        t[r][tx] = v;
        bf hi, lo; split_bf16(v, hi, lo);
        x1[(long)b * SS * DD + (long)(r0 + r) * DD + c0 + tx] = hi;
        bf* d = x3 + (long)b * SS * 3 * DD + (long)(r0 + r) * 3 * DD + 3 * (c0 + tx);
        d[0] = hi; d[1] = hi; d[2] = lo;
    }
    __syncthreads();
#pragma unroll
    for (int p = 0; p < 4; ++p) {
        const int rr = ty + 8 * p;
        xT1[(long)b * DD * SS + (long)(c0 + rr) * SS + r0 + tx] = __float2bfloat16(t[tx][rr]);
    }
}

// ---------------------------------------------------------------------------
// qkv fp32 (G x S x 2048) -> q3 (cols<1024, A-form [hi,hi,lo]) and
//                            k3 (cols>=1024, B-form [hi,lo,hi])
// ---------------------------------------------------------------------------
__global__ __launch_bounds__(256) void split_qk_kernel(
    const float* __restrict__ qkv, bf* __restrict__ q3, bf* __restrict__ k3, long n)
{
    long i = (long)blockIdx.x * 256 + threadIdx.x;
    if (i >= n) return;
    const long row = i >> 11;           // global row (b*1024 + s)
    const int c = (int)(i & 2047);
    bf hi, lo; split_bf16(qkv[i], hi, lo);
    if (c < 1024) {
        bf* d = q3 + row * 3072 + 3 * c;
        d[0] = hi; d[1] = hi; d[2] = lo;
    } else {
        bf* d = k3 + row * 3072 + 3 * (c - 1024);
        d[0] = hi; d[1] = lo; d[2] = hi;
    }
}

// ---------------------------------------------------------------------------
// L2-normalize each half-row (1024) of ctx fp32 (rows 2048) -> bf16 out
// grid G*S*2, block 256
// ---------------------------------------------------------------------------
__global__ __launch_bounds__(256) void l2norm_conv_kernel(
    const float* __restrict__ ctx, bf* __restrict__ ctx_bf)
{
    __shared__ float red[4];
    const long row = blockIdx.x >> 1;
    const int half = blockIdx.x & 1;
    const float* p = ctx + row * 2048 + half * 1024;
    bf* q = ctx_bf + row * 2048 + half * 1024;
    const int t = threadIdx.x;

    float v[4];
    float ss = 0.0f;
#pragma unroll
    for (int i = 0; i < 4; ++i) { v[i] = p[t + 256 * i]; ss = fmaf(v[i], v[i], ss); }
    ss = blockReduceSum(ss, red);
    const float inv = 1.0f / fmaxf(sqrtf(ss), 1e-12f);
#pragma unroll
    for (int i = 0; i < 4; ++i) q[t + 256 * i] = __float2bfloat16(v[i] * inv);
}

// ---------------------------------------------------------------------------
// softmax -> mask -> L1 renorm, row 1024, fp32 in -> bf16 out. grid G*S.
// ---------------------------------------------------------------------------
__global__ __launch_bounds__(256) void softmax_mask_kernel(
    const float* __restrict__ attn, const int* __restrict__ mask, bf* __restrict__ attn_bf)
{
    __shared__ float red[4];
    const long row = blockIdx.x;
    const float* p = attn + row * SS;
    const int* mrow = mask + row * SS;
    bf* o = attn_bf + row * SS;
    const int t = threadIdx.x;

    float v[4];
    int mv[4];
#pragma unroll
    for (int i = 0; i < 4; ++i) { v[i] = p[t + 256 * i]; mv[i] = mrow[t + 256 * i]; }
    float mx = fmaxf(fmaxf(v[0], v[1]), fmaxf(v[2], v[3]));
    mx = blockReduceMax(mx, red);

    float e[4];
    float s = 0.0f;
#pragma unroll
    for (int i = 0; i < 4; ++i) { e[i] = expf(v[i] - mx); s += e[i]; }
    s = blockReduceSum(s, red);

    float l1 = 0.0f;
#pragma unroll
    for (int i = 0; i < 4; ++i) { e[i] = mv[i] ? e[i] / s : 0.0f; l1 += e[i]; }
    l1 = blockReduceSum(l1, red);
    const float inv = 1.0f / fmaxf(l1, 1e-12f);
#pragma unroll
    for (int i = 0; i < 4; ++i) o[t + 256 * i] = __float2bfloat16(e[i] * inv);
}

// ---------------------------------------------------------------------------
extern "C" void kernel_launch(void* const* d_in, const int* in_sizes, int n_in,
                              void* d_out, int out_size, void* d_ws, size_t ws_size,
                              hipStream_t stream)
{
    const float* x    = (const float*)d_in[0];
    const int*   mask = (const int*)d_in[1];
    const float* Wqkv = (const float*)d_in[2];
    const float* bqkv = (const float*)d_in[3];
    const float* Wctx = (const float*)d_in[4];
    const float* bctx = (const float*)d_in[5];
    const float* Wf   = (const float*)d_in[6];
    const float* bfp  = (const float*)d_in[7];
    const float* Wo   = (const float*)d_in[8];
    const float* bo   = (const float*)d_in[9];
    float* out = (float*)d_out;

    const long SD = (long)SS * DD;

    auto align_up = [](size_t v) { return (v + 255) & ~(size_t)255; };

    // Shared (batch-independent) weight buffers
    const size_t sz_Wqkv3 = 2048L * 3072 * 2;
    const size_t sz_Wctx1 = 2048L * 1024 * 2;
    const size_t sz_Wo    = 1024L * 1024 * 2;
    const size_t SH = align_up(sz_Wqkv3) + align_up(sz_Wctx1) + 2 * align_up(sz_Wo);

    // Per-batch buffers (k3 aliases x3)
    const size_t sz_x3   = (size_t)SS * 3 * DD * 2;   // also k3
    const size_t sz_x1   = (size_t)SS * DD * 2;
    const size_t sz_xT1  = (size_t)DD * SS * 2;
    const size_t sz_big  = (size_t)SS * 2 * EE * 4;   // qkv fp32, later ctx fp32
    const size_t sz_q3   = (size_t)SS * 3 * EE * 2;
    const size_t sz_attn = (size_t)SS * SS * 4;
    const size_t sz_attnb= (size_t)SS * SS * 2;
    const size_t sz_Y1   = (size_t)2 * SS * DD * 2;
    const size_t sz_ctxb = (size_t)SS * 2 * SS * 2;
    const size_t sz_valb = (size_t)SS * DD * 2;
    const size_t PB = align_up(sz_x3) + align_up(sz_x1) + align_up(sz_xT1) +
                      align_up(sz_big) + align_up(sz_q3) + align_up(sz_attn) +
                      align_up(sz_attnb) + align_up(sz_Y1) + align_up(sz_ctxb) +
                      align_up(sz_valb);

    int G = 16;
    while (G > 1 && SH + (size_t)G * PB > ws_size) G >>= 1;

    char* p = (char*)d_ws;
    auto take = [&](size_t bytes) { char* r = p; p += align_up(bytes); return r; };
    bf* Wqkv3 = (bf*)take(sz_Wqkv3);
    bf* Wctx1 = (bf*)take(sz_Wctx1);
    bf* Wo1b  = (bf*)take(sz_Wo);
    bf* Wo2b  = (bf*)take(sz_Wo);
    bf* x3    = (bf*)take((size_t)G * sz_x3);
    bf* k3    = x3;  // alias: x3 dead after GEMM1, k3 written after
    bf* x1    = (bf*)take((size_t)G * sz_x1);
    bf* xT1   = (bf*)take((size_t)G * sz_xT1);
    float* big  = (float*)take((size_t)G * sz_big);
    bf* q3    = (bf*)take((size_t)G * sz_q3);
    float* attn = (float*)take((size_t)G * sz_attn);
    bf* attn_bf = (bf*)take((size_t)G * sz_attnb);
    bf* Y1    = (bf*)take((size_t)G * sz_Y1);
    bf* ctx_bf= (bf*)take((size_t)G * sz_ctxb);
    bf* val_bf= (bf*)take((size_t)G * sz_valb);

    const dim3 blk(256);

    // --- weight conversions (once) ---
    split3B_kernel<<<dim3((2048L * 1024) / 256), blk, 0, stream>>>(Wqkv, Wqkv3, 1024, 1024, 2048L * 1024);
    conv_kernel<<<dim3((2048L * 1024) / 256), blk, 0, stream>>>(Wctx, Wctx1, 1024, 1024, 2048L * 1024);
    conv_kernel<<<dim3((1024L * 1024) / 256), blk, 0, stream>>>(Wo, Wo1b, 1024, 2048, 1024L * 1024);
    conv_kernel<<<dim3((1024L * 1024) / 256), blk, 0, stream>>>(Wo + 1024, Wo2b, 1024, 2048, 1024L * 1024);

    for (int bc0 = 0; bc0 < BB; bc0 += G) {
        const float* xb = x + (long)bc0 * SD;

        // x -> x3 / x1 / xT1
        conv_x_kernel<<<dim3(32, 32, G), blk, 0, stream>>>(xb, x3, x1, xT1);

        // 1. qkv = x * Wqkv^T + bqkv   (split-3, K=3072) -> big fp32
        gemm_bf16_nt<false><<<dim3(16, 8, G), blk, 0, stream>>>(
            x3, (long)SS * 3 * DD, 3 * DD, Wqkv3, 0, 3 * DD,
            big, nullptr, (long)SS * 2 * EE, 2 * EE, 3 * DD,
            bqkv, nullptr, 0, nullptr, 0);

        // qkv -> q3 (A-form), k3 (B-form)
        split_qk_kernel<<<dim3((unsigned)((long)G * SS * 2048 / 256)), blk, 0, stream>>>(
            big, q3, k3, (long)G * SS * 2048);

        // 2. attn = Wf0 * q k^T + bf   (split-3, K=3072)
        gemm_bf16_nt<false><<<dim3(8, 8, G), blk, 0, stream>>>(
            q3, (long)SS * 3 * EE, 3 * EE, k3, (long)SS * 3 * EE, 3 * EE,
            attn, nullptr, (long)SS * SS, SS, 3 * EE,
            nullptr, Wf, 0, bfp, 0);

        // 3. Y1 = Wctx * x  (NT via xT1), bf16 out
        gemm_bf16_nt<true><<<dim3(8, 16, G), blk, 0, stream>>>(
            Wctx1, 0, 1024, xT1, (long)DD * SS, 1024,
            nullptr, Y1, (long)2 * SS * DD, 1024, 1024,
            nullptr, nullptr, 0, nullptr, 0);

        // 4. ctx = x * Y^T + bctx -> big fp32 (reuses qkv buffer)
        gemm_bf16_nt<false><<<dim3(16, 8, G), blk, 0, stream>>>(
            x1, SD, 1024, Y1, (long)2 * SS * DD, 1024,
            big, nullptr, (long)SS * 2 * SS, 2048, 1024,
            bctx, nullptr, 0, nullptr, 0);

        // 5. L2-normalize halves -> ctx_bf
        l2norm_conv_kernel<<<dim3(G * SS * 2), blk, 0, stream>>>(big, ctx_bf);

        // 6. attn += Wf1 * ctx_q ctx_k^T
        gemm_bf16_nt<false><<<dim3(8, 8, G), blk, 0, stream>>>(
            ctx_bf, (long)SS * 2 * SS, 2048, ctx_bf + 1024, (long)SS * 2 * SS, 2048,
            attn, nullptr, (long)SS * SS, SS, 1024,
            nullptr, Wf, 1, nullptr, 1);

        // 7. softmax -> mask -> L1 renorm -> bf16
        softmax_mask_kernel<<<dim3(G * SS), blk, 0, stream>>>(
            attn, mask + (long)bc0 * SS * SS, attn_bf);

        // 8. values = attn * x (NT via xT1), bf16 out
        gemm_bf16_nt<true><<<dim3(8, 8, G), blk, 0, stream>>>(
            attn_bf, (long)SS * SS, 1024, xT1, (long)DD * SS, 1024,
            nullptr, val_bf, SD, 1024, 1024,
            nullptr, nullptr, 0, nullptr, 0);

        // 9. out = x * Wo1^T + bo
        gemm_bf16_nt<false><<<dim3(8, 8, G), blk, 0, stream>>>(
            x1, SD, 1024, Wo1b, 0, 1024,
            out + (long)bc0 * SD, nullptr, SD, 1024, 1024,
            bo, nullptr, 0, nullptr, 0);

        // 10. out += values * Wo2^T
        gemm_bf16_nt<false><<<dim3(8, 8, G), blk, 0, stream>>>(
            val_bf, SD, 1024, Wo2b, 0, 1024,
            out + (long)bc0 * SD, nullptr, SD, 1024, 1024,
            nullptr, nullptr, 0, nullptr, 1);
    }
}

// Round 4
// 1507.782 us; speedup vs baseline: 3.5820x; 1.2350x over previous
//
#include <hip/hip_runtime.h>
#include <hip/hip_bf16.h>

// Problem constants
#define BB 16
#define SS 1024
#define DD 1024
#define EE 1024

typedef __hip_bfloat16 bf;
using s8v   = __attribute__((ext_vector_type(8))) short;
using f32x4 = __attribute__((ext_vector_type(4))) float;

// ---------------------------------------------------------------------------
// bf16 NT GEMM with MFMA 16x16x32. 128x128 tile, 4 waves (2x2), 64x64/wave.
//   C[m,n] (+)= alpha * sum_k A[m,k]*B[n,k]  (+ bias[n]) (+ addc)
// EP=0: fp32 out (optional accumulate). EP=1: bf16 out. EP=2: QKSPLIT —
//   v = acc + Cp[off]; hi/lo split; col<1024 -> Q planes [hi|lo],
//   col>=1024 -> K planes [lo|hi] (both row stride 2048 bf16).
// M,N multiples of 128, K multiple of 32.
// ---------------------------------------------------------------------------
template <int EP>
__global__ __launch_bounds__(256) void gemm_bf16_nt(
    const bf* __restrict__ A, long sA, int lda,
    const bf* __restrict__ B, long sB, int ldb,
    float* __restrict__ C, bf* __restrict__ Cb,
    bf* __restrict__ qp, bf* __restrict__ kp,
    long sC, int ldc, int K,
    const float* __restrict__ bias,
    const float* __restrict__ alpha_ptr, int alpha_idx,
    const float* __restrict__ addc_ptr,
    int accumulate)
{
    __shared__ __align__(16) unsigned short As[128][40];
    __shared__ __align__(16) unsigned short Bs[128][40];

    const int tid  = threadIdx.x;
    const int wave = tid >> 6, lane = tid & 63;
    const int wm = (wave >> 1) * 64, wn = (wave & 1) * 64;
    const int lm = lane & 15, quad = lane >> 4;

    const int m0 = blockIdx.y * 128, n0 = blockIdx.x * 128;
    const bf* Ab = A + (long)blockIdx.z * sA;
    const bf* Bb = B + (long)blockIdx.z * sB;

    // Staging: 128 rows x 32 cols = 512 chunks of 16B per matrix, 2/thread.
    const int r0 = tid >> 2;
    const int r1 = (tid + 256) >> 2;
    const int c0c = (tid & 3) << 3;

    f32x4 acc[4][4];
#pragma unroll
    for (int i = 0; i < 4; ++i)
#pragma unroll
        for (int j = 0; j < 4; ++j)
            acc[i][j] = (f32x4){0.f, 0.f, 0.f, 0.f};

    for (int k0 = 0; k0 < K; k0 += 32) {
        const s8v av0 = *(const s8v*)(Ab + (long)(m0 + r0) * lda + k0 + c0c);
        const s8v av1 = *(const s8v*)(Ab + (long)(m0 + r1) * lda + k0 + c0c);
        const s8v bv0 = *(const s8v*)(Bb + (long)(n0 + r0) * ldb + k0 + c0c);
        const s8v bv1 = *(const s8v*)(Bb + (long)(n0 + r1) * ldb + k0 + c0c);

        __syncthreads();
        *(s8v*)&As[r0][c0c] = av0;
        *(s8v*)&As[r1][c0c] = av1;
        *(s8v*)&Bs[r0][c0c] = bv0;
        *(s8v*)&Bs[r1][c0c] = bv1;
        __syncthreads();

        s8v a[4], b[4];
#pragma unroll
        for (int i = 0; i < 4; ++i) a[i] = *(const s8v*)&As[wm + 16 * i + lm][quad * 8];
#pragma unroll
        for (int j = 0; j < 4; ++j) b[j] = *(const s8v*)&Bs[wn + 16 * j + lm][quad * 8];
#pragma unroll
        for (int i = 0; i < 4; ++i)
#pragma unroll
            for (int j = 0; j < 4; ++j)
                acc[i][j] = __builtin_amdgcn_mfma_f32_16x16x32_bf16(a[i], b[j], acc[i][j], 0, 0, 0);
    }

    const float alpha = alpha_ptr ? alpha_ptr[alpha_idx] : 1.0f;
    const float addc  = addc_ptr ? addc_ptr[0] : 0.0f;
    float* Cp = C ? C + (long)blockIdx.z * sC : nullptr;
    bf* Cbp = (EP == 1) ? Cb + (long)blockIdx.z * sC : nullptr;

#pragma unroll
    for (int i = 0; i < 4; ++i) {
#pragma unroll
        for (int j = 0; j < 4; ++j) {
            const int cidx = n0 + wn + 16 * j + lm;
            const float bv = bias ? bias[cidx] : 0.0f;
            const long rbase = m0 + wm + 16 * i + quad * 4;
#pragma unroll
            for (int r = 0; r < 4; ++r) {
                float v = alpha * acc[i][j][r] + addc + bv;
                const long row = rbase + r;
                const long off = row * (long)ldc + cidx;
                if (EP == 2) {
                    v += Cp[off];  // accumulate partial from plane pass 1
                    bf hi = __float2bfloat16(v);
                    bf lo = __float2bfloat16(v - __bfloat162float(hi));
                    if (cidx < 1024) {
                        qp[row * 2048 + cidx] = hi;
                        qp[row * 2048 + 1024 + cidx] = lo;
                    } else {
                        const int c = cidx - 1024;
                        kp[row * 2048 + 1024 + c] = hi;
                        kp[row * 2048 + c] = lo;
                    }
                } else if (EP == 1) {
                    Cbp[off] = __float2bfloat16(v);
                } else {
                    if (accumulate) v += Cp[off];
                    Cp[off] = v;
                }
            }
        }
    }
}

// ---------------------------------------------------------------------------
// Block reductions (256 threads = 4 waves of 64)
// ---------------------------------------------------------------------------
__device__ inline float blockReduceSum(float v, float* red)
{
#pragma unroll
    for (int off = 32; off > 0; off >>= 1) v += __shfl_xor(v, off, 64);
    __syncthreads();
    if ((threadIdx.x & 63) == 0) red[threadIdx.x >> 6] = v;
    __syncthreads();
    return red[0] + red[1] + red[2] + red[3];
}

__device__ inline float blockReduceMax(float v, float* red)
{
#pragma unroll
    for (int off = 32; off > 0; off >>= 1) v = fmaxf(v, __shfl_xor(v, off, 64));
    __syncthreads();
    if ((threadIdx.x & 63) == 0) red[threadIdx.x >> 6] = v;
    __syncthreads();
    return fmaxf(fmaxf(red[0], red[1]), fmaxf(red[2], red[3]));
}

__device__ inline void split_bf16(float v, bf& hi, bf& lo)
{
    hi = __float2bfloat16(v);
    lo = __float2bfloat16(v - __bfloat162float(hi));
}

// ---------------------------------------------------------------------------
// Weight prep (once per launch)
// ---------------------------------------------------------------------------
// Wqkv (2048x1024 fp32) -> Whihi (2048x2048: [hi|hi]) and Wlo (2048x1024)
__global__ __launch_bounds__(256) void prep_wqkv_kernel(
    const float* __restrict__ W, bf* __restrict__ whihi, bf* __restrict__ wlo)
{
    long i = (long)blockIdx.x * 256 + threadIdx.x;   // 2048*1024 threads
    long r = i >> 10; int c = (int)(i & 1023);
    bf hi, lo; split_bf16(W[i], hi, lo);
    whihi[r * 2048 + c] = hi;
    whihi[r * 2048 + 1024 + c] = hi;
    wlo[i] = lo;
}

// plain fp32 -> bf16 with source stride
__global__ __launch_bounds__(256) void conv_kernel(
    const float* __restrict__ src, bf* __restrict__ dst, int cols, int src_ld, long n)
{
    long i = (long)blockIdx.x * 256 + threadIdx.x;
    if (i >= n) return;
    long r = i / cols; int c = (int)(i % cols);
    dst[i] = __float2bfloat16(src[r * src_ld + c]);
}

// ---------------------------------------------------------------------------
// x -> xhl (S x 2048: [hi|lo]) and xT1 (D x S, bf16 hi). grid (32,32,G).
// ---------------------------------------------------------------------------
__global__ __launch_bounds__(256) void conv_x_kernel(
    const float* __restrict__ x, bf* __restrict__ xhl, bf* __restrict__ xT1)
{
    __shared__ float t[32][33];
    const int b = blockIdx.z;
    const int c0 = blockIdx.x * 32, r0 = blockIdx.y * 32;
    const int tx = threadIdx.x & 31, ty = threadIdx.x >> 5;  // ty 0..7
    const float* xb = x + (long)b * SS * DD;
    bf* xhlb = xhl + (long)b * SS * 2048;
#pragma unroll
    for (int p = 0; p < 4; ++p) {
        const int r = ty + 8 * p;
        const float v = xb[(long)(r0 + r) * DD + c0 + tx];
        t[r][tx] = v;
        bf hi, lo; split_bf16(v, hi, lo);
        xhlb[(long)(r0 + r) * 2048 + c0 + tx] = hi;
        xhlb[(long)(r0 + r) * 2048 + 1024 + c0 + tx] = lo;
    }
    __syncthreads();
#pragma unroll
    for (int p = 0; p < 4; ++p) {
        const int rr = ty + 8 * p;
        xT1[(long)b * DD * SS + (long)(c0 + rr) * SS + r0 + tx] =
            __float2bfloat16(t[tx][rr]);
    }
}

// ---------------------------------------------------------------------------
// L2-normalize each half-row (1024) of ctx fp32 (rows of 2048) -> bf16 out
// grid = nrows*2, block 256.
// ---------------------------------------------------------------------------
__global__ __launch_bounds__(256) void l2norm_conv_kernel(
    const float* __restrict__ ctx, bf* __restrict__ ctx_bf)
{
    __shared__ float red[4];
    const long row = blockIdx.x >> 1;
    const int half = blockIdx.x & 1;
    const float* p = ctx + row * 2048 + half * 1024;
    bf* q = ctx_bf + row * 2048 + half * 1024;
    const int t = threadIdx.x;

    float v[4];
    float ss = 0.0f;
#pragma unroll
    for (int i = 0; i < 4; ++i) { v[i] = p[t + 256 * i]; ss = fmaf(v[i], v[i], ss); }
    ss = blockReduceSum(ss, red);
    const float inv = 1.0f / fmaxf(sqrtf(ss), 1e-12f);
#pragma unroll
    for (int i = 0; i < 4; ++i) q[t + 256 * i] = __float2bfloat16(v[i] * inv);
}

// ---------------------------------------------------------------------------
// softmax -> mask -> L1 renorm, row 1024, fp32 in -> bf16 out. grid = nrows.
// ---------------------------------------------------------------------------
__global__ __launch_bounds__(256) void softmax_mask_kernel(
    const float* __restrict__ attn, const int* __restrict__ mask, bf* __restrict__ attn_bf)
{
    __shared__ float red[4];
    const long row = blockIdx.x;
    const float* p = attn + row * SS;
    const int* mrow = mask + row * SS;
    bf* o = attn_bf + row * SS;
    const int t = threadIdx.x;

    float v[4];
    int mv[4];
#pragma unroll
    for (int i = 0; i < 4; ++i) { v[i] = p[t + 256 * i]; mv[i] = mrow[t + 256 * i]; }
    float mx = fmaxf(fmaxf(v[0], v[1]), fmaxf(v[2], v[3]));
    mx = blockReduceMax(mx, red);

    float e[4];
    float s = 0.0f;
#pragma unroll
    for (int i = 0; i < 4; ++i) { e[i] = expf(v[i] - mx); s += e[i]; }
    s = blockReduceSum(s, red);

    float l1 = 0.0f;
#pragma unroll
    for (int i = 0; i < 4; ++i) { e[i] = mv[i] ? e[i] / s : 0.0f; l1 += e[i]; }
    l1 = blockReduceSum(l1, red);
    const float inv = 1.0f / fmaxf(l1, 1e-12f);
#pragma unroll
    for (int i = 0; i < 4; ++i) o[t + 256 * i] = __float2bfloat16(e[i] * inv);
}

// ---------------------------------------------------------------------------
extern "C" void kernel_launch(void* const* d_in, const int* in_sizes, int n_in,
                              void* d_out, int out_size, void* d_ws, size_t ws_size,
                              hipStream_t stream)
{
    const float* x    = (const float*)d_in[0];
    const int*   mask = (const int*)d_in[1];
    const float* Wqkv = (const float*)d_in[2];
    const float* bqkv = (const float*)d_in[3];
    const float* Wctx = (const float*)d_in[4];
    const float* bctx = (const float*)d_in[5];
    const float* Wf   = (const float*)d_in[6];
    const float* bfp  = (const float*)d_in[7];
    const float* Wo   = (const float*)d_in[8];
    const float* bo   = (const float*)d_in[9];
    float* out = (float*)d_out;

    const long SD = (long)SS * DD;                 // 1M elements per batch

    auto align_up = [](size_t v) { return (v + 255) & ~(size_t)255; };

    // Shared weight buffers
    const size_t sz_whihi = 2048L * 2048 * 2;      // 8.39 MB
    const size_t sz_wlo   = 2048L * 1024 * 2;      // 4.19 MB
    const size_t sz_wctx  = 2048L * 1024 * 2;      // 4.19 MB
    const size_t sz_wo    = 1024L * 1024 * 2;      // 2.1 MB
    const size_t SH = align_up(sz_whihi) + align_up(sz_wlo) + align_up(sz_wctx) +
                      2 * align_up(sz_wo);

    // Per-batch pooled regions:
    //   R1 (8.39 MB): qkvf fp32 -> ctxf fp32 -> {attnb, valb}
    //   R2 (4.19 MB): Qbuf -> ctxb
    //   R3 (4.19 MB): Kbuf -> Y1
    //   R4 (4.19 MB): attn fp32
    //   R5 (4.19 MB): xhl
    //   R6 (2.10 MB): xT1
    const size_t szR1 = 1024L * 2048 * 4;
    const size_t szR2 = 1024L * 2048 * 2;
    const size_t szR3 = 1024L * 2048 * 2;
    const size_t szR4 = 1024L * 1024 * 4;
    const size_t szR5 = 1024L * 2048 * 2;
    const size_t szR6 = 1024L * 1024 * 2;
    const size_t PB = align_up(szR1) + align_up(szR2) + align_up(szR3) +
                      align_up(szR4) + align_up(szR5) + align_up(szR6);

    int G = 16;
    while (G > 1 && SH + (size_t)G * PB > ws_size) G >>= 1;

    char* p = (char*)d_ws;
    auto take = [&](size_t bytes) { char* r = p; p += align_up(bytes); return r; };
    bf* Whihi = (bf*)take(sz_whihi);
    bf* Wlo   = (bf*)take(sz_wlo);
    bf* Wctx1 = (bf*)take(sz_wctx);
    bf* Wo1b  = (bf*)take(sz_wo);
    bf* Wo2b  = (bf*)take(sz_wo);
    char* R1 = take((size_t)G * szR1);
    char* R2 = take((size_t)G * szR2);
    char* R3 = take((size_t)G * szR3);
    char* R4 = take((size_t)G * szR4);
    char* R5 = take((size_t)G * szR5);
    char* R6 = take((size_t)G * szR6);

    float* qkvf = (float*)R1;                        // G x (1024 x 2048) fp32
    float* ctxf = (float*)R1;                        // G x (1024 x 2048) fp32
    bf* attnb   = (bf*)R1;                           // G x (1024 x 1024) bf16
    bf* valb    = (bf*)(R1 + (size_t)G * 1024 * 1024 * 2);
    bf* Qbuf = (bf*)R2;                              // G x (1024 x 2048) [hi|lo]
    bf* ctxb = (bf*)R2;
    bf* Kbuf = (bf*)R3;                              // G x (1024 x 2048) [lo|hi]
    bf* Y1   = (bf*)R3;                              // G x (2048 x 1024)
    float* attn = (float*)R4;                        // G x (1024 x 1024) fp32
    bf* xhl = (bf*)R5;                               // G x (1024 x 2048) [hi|lo]
    bf* xT1 = (bf*)R6;                               // G x (1024 x 1024)

    const dim3 blk(256);
    const long sQ = 1024L * 2048;                    // per-batch stride, Q/K/xhl/ctx
    const long sAT = 1024L * 1024;

    // --- weight prep (once) ---
    prep_wqkv_kernel<<<dim3((2048L * 1024) / 256), blk, 0, stream>>>(Wqkv, Whihi, Wlo);
    conv_kernel<<<dim3((2048L * 1024) / 256), blk, 0, stream>>>(Wctx, Wctx1, 1024, 1024, 2048L * 1024);
    conv_kernel<<<dim3((1024L * 1024) / 256), blk, 0, stream>>>(Wo, Wo1b, 1024, 2048, 1024L * 1024);
    conv_kernel<<<dim3((1024L * 1024) / 256), blk, 0, stream>>>(Wo + 1024, Wo2b, 1024, 2048, 1024L * 1024);

    for (int bc0 = 0; bc0 < BB; bc0 += G) {
        const float* xb = x + (long)bc0 * SD;
        const int M = G * 1024;                      // flattened rows this chunk

        // 0. x -> xhl, xT1
        conv_x_kernel<<<dim3(32, 32, G), blk, 0, stream>>>(xb, xhl, xT1);

        // 1a. qkvf = [xhi|xlo] * [Whi|Whi]^T + bqkv   (K=2048, flattened M)
        gemm_bf16_nt<0><<<dim3(16, M / 128), blk, 0, stream>>>(
            xhl, 0, 2048, Whihi, 0, 2048,
            qkvf, nullptr, nullptr, nullptr, 0, 2048, 2048,
            bqkv, nullptr, 0, nullptr, 0);

        // 1b. qkvf += xhi * Wlo^T; split-write Qbuf ([hi|lo]) / Kbuf ([lo|hi])
        gemm_bf16_nt<2><<<dim3(16, M / 128), blk, 0, stream>>>(
            xhl, 0, 2048, Wlo, 0, 1024,
            qkvf, nullptr, Qbuf, Kbuf, 0, 2048, 1024,
            nullptr, nullptr, 0, nullptr, 1);

        // 2a. attn = Wf0 * (Qhi Khi^T) + bf          (K=1024, per batch)
        gemm_bf16_nt<0><<<dim3(8, 8, G), blk, 0, stream>>>(
            Qbuf, sQ, 2048, Kbuf + 1024, sQ, 2048,
            attn, nullptr, nullptr, nullptr, sAT, 1024, 1024,
            nullptr, Wf, 0, bfp, 0);

        // 2b. attn += Wf0 * (Q [Klo|Khi]^T)          (K=2048: qhi*klo + qlo*khi)
        gemm_bf16_nt<0><<<dim3(8, 8, G), blk, 0, stream>>>(
            Qbuf, sQ, 2048, Kbuf, sQ, 2048,
            attn, nullptr, nullptr, nullptr, sAT, 1024, 2048,
            nullptr, Wf, 0, nullptr, 1);

        // 3. Y1 = Wctx * x^T  (NT via xT1), bf16 out (per batch)
        gemm_bf16_nt<1><<<dim3(8, 16, G), blk, 0, stream>>>(
            Wctx1, 0, 1024, xT1, sAT, 1024,
            nullptr, Y1, nullptr, nullptr, sQ, 1024, 1024,
            nullptr, nullptr, 0, nullptr, 0);

        // 4. ctxf = xhi * Y1^T + bctx                (per batch)
        gemm_bf16_nt<0><<<dim3(16, 8, G), blk, 0, stream>>>(
            xhl, sQ, 2048, Y1, sQ, 1024,
            ctxf, nullptr, nullptr, nullptr, sQ, 2048, 1024,
            bctx, nullptr, 0, nullptr, 0);

        // 5. L2-normalize halves -> ctxb
        l2norm_conv_kernel<<<dim3(G * 1024 * 2), blk, 0, stream>>>(ctxf, ctxb);

        // 6. attn += Wf1 * ctx_q ctx_k^T
        gemm_bf16_nt<0><<<dim3(8, 8, G), blk, 0, stream>>>(
            ctxb, sQ, 2048, ctxb + 1024, sQ, 2048,
            attn, nullptr, nullptr, nullptr, sAT, 1024, 1024,
            nullptr, Wf, 1, nullptr, 1);

        // 7. softmax -> mask -> L1 renorm -> attnb
        softmax_mask_kernel<<<dim3(G * 1024), blk, 0, stream>>>(
            attn, mask + (long)bc0 * SS * SS, attnb);

        // 8. valb = attnb * x^T (NT via xT1), bf16 out (per batch)
        gemm_bf16_nt<1><<<dim3(8, 8, G), blk, 0, stream>>>(
            attnb, sAT, 1024, xT1, sAT, 1024,
            nullptr, valb, nullptr, nullptr, sAT, 1024, 1024,
            nullptr, nullptr, 0, nullptr, 0);

        // 9. out = xhi * Wo1^T + bo                  (flattened M)
        gemm_bf16_nt<0><<<dim3(8, M / 128), blk, 0, stream>>>(
            xhl, 0, 2048, Wo1b, 0, 1024,
            out + (long)bc0 * SD, nullptr, nullptr, nullptr, 0, 1024, 1024,
            bo, nullptr, 0, nullptr, 0);

        // 10. out += valb * Wo2^T                    (flattened M)
        gemm_bf16_nt<0><<<dim3(8, M / 128), blk, 0, stream>>>(
            valb, 0, 1024, Wo2b, 0, 1024,
            out + (long)bc0 * SD, nullptr, nullptr, nullptr, 0, 1024, 1024,
            nullptr, nullptr, 0, nullptr, 1);
    }
}

// Round 5
// 1505.942 us; speedup vs baseline: 3.5864x; 1.0012x over previous
//
#include <hip/hip_runtime.h>
#include <hip/hip_bf16.h>

// Problem constants
#define BB 16
#define SS 1024
#define DD 1024
#define EE 1024

typedef __hip_bfloat16 bf;
using s8v   = __attribute__((ext_vector_type(8))) short;
using f32x4 = __attribute__((ext_vector_type(4))) float;

// Async global->LDS, 16 B per lane. LDS dest = wave-uniform base + lane*16.
__device__ __forceinline__ void gload16(const bf* g, unsigned short* l)
{
    __builtin_amdgcn_global_load_lds(
        (const __attribute__((address_space(1))) void*)g,
        (__attribute__((address_space(3))) void*)l,
        16, 0, 0);
}

// ---------------------------------------------------------------------------
// bf16 NT GEMM with MFMA 16x16x32. 128x128 tile, 4 waves (2x2), 64x64/wave.
// Staging via global_load_lds width=16 (m97 structure, ~874 TF class).
//   C[m,n] (+)= alpha * sum_k A[m,k]*B[n,k]  (+ bias[n]) (+ addc)
// EP=0: fp32 out (optional accumulate). EP=1: bf16 out. EP=2: QKSPLIT —
//   v = acc + Cp[off]; hi/lo split; col<1024 -> Q planes [hi|lo],
//   col>=1024 -> K planes [lo|hi] (both row stride 2048 bf16).
// M,N multiples of 128, K multiple of 32.
// ---------------------------------------------------------------------------
template <int EP>
__global__ __launch_bounds__(256) void gemm_bf16_nt(
    const bf* __restrict__ A, long sA, int lda,
    const bf* __restrict__ B, long sB, int ldb,
    float* __restrict__ C, bf* __restrict__ Cb,
    bf* __restrict__ qp, bf* __restrict__ kp,
    long sC, int ldc, int K,
    const float* __restrict__ bias,
    const float* __restrict__ alpha_ptr, int alpha_idx,
    const float* __restrict__ addc_ptr,
    int accumulate)
{
    // Unpadded row-major tiles: 128 rows x 32 bf16 (64 B/row) = 8 KB each.
    __shared__ __align__(16) unsigned short As[128 * 32];
    __shared__ __align__(16) unsigned short Bs[128 * 32];

    const int tid  = threadIdx.x;
    const int wave = tid >> 6, lane = tid & 63;
    const int wm = (wave >> 1) * 64, wn = (wave & 1) * 64;
    const int lm = lane & 15, quad = lane >> 4;

    const int m0 = blockIdx.y * 128, n0 = blockIdx.x * 128;
    const bf* Ab = A + (long)blockIdx.z * sA;
    const bf* Bb = B + (long)blockIdx.z * sB;

    // Staging map: wave w covers tile rows [w*32, w*32+32), two 1-KB issues
    // (16 rows each). Lane i -> row = base + i/4, col = (i%4)*8 (16 B).
    const int srow = wave * 32 + (lane >> 2);   // issue-0 row for this lane
    const int scol = (lane & 3) * 8;            // bf16 column offset
    unsigned short* lA0 = &As[(wave * 32) * 32];
    unsigned short* lA1 = &As[(wave * 32 + 16) * 32];
    unsigned short* lB0 = &Bs[(wave * 32) * 32];
    unsigned short* lB1 = &Bs[(wave * 32 + 16) * 32];

    f32x4 acc[4][4];
#pragma unroll
    for (int i = 0; i < 4; ++i)
#pragma unroll
        for (int j = 0; j < 4; ++j)
            acc[i][j] = (f32x4){0.f, 0.f, 0.f, 0.f};

    const bf* gA0 = Ab + (long)(m0 + srow) * lda + scol;
    const bf* gA1 = Ab + (long)(m0 + srow + 16) * lda + scol;
    const bf* gB0 = Bb + (long)(n0 + srow) * ldb + scol;
    const bf* gB1 = Bb + (long)(n0 + srow + 16) * ldb + scol;

    for (int k0 = 0; k0 < K; k0 += 32) {
        __syncthreads();                 // prior iter's ds_reads complete
        gload16(gA0 + k0, lA0);
        gload16(gA1 + k0, lA1);
        gload16(gB0 + k0, lB0);
        gload16(gB1 + k0, lB1);
        __syncthreads();                 // drains vmcnt -> LDS visible

        s8v a[4], b[4];
#pragma unroll
        for (int i = 0; i < 4; ++i) a[i] = *(const s8v*)&As[(wm + 16 * i + lm) * 32 + quad * 8];
#pragma unroll
        for (int j = 0; j < 4; ++j) b[j] = *(const s8v*)&Bs[(wn + 16 * j + lm) * 32 + quad * 8];
#pragma unroll
        for (int i = 0; i < 4; ++i)
#pragma unroll
            for (int j = 0; j < 4; ++j)
                acc[i][j] = __builtin_amdgcn_mfma_f32_16x16x32_bf16(a[i], b[j], acc[i][j], 0, 0, 0);
    }

    const float alpha = alpha_ptr ? alpha_ptr[alpha_idx] : 1.0f;
    const float addc  = addc_ptr ? addc_ptr[0] : 0.0f;
    float* Cp = C ? C + (long)blockIdx.z * sC : nullptr;
    bf* Cbp = (EP == 1) ? Cb + (long)blockIdx.z * sC : nullptr;

#pragma unroll
    for (int i = 0; i < 4; ++i) {
#pragma unroll
        for (int j = 0; j < 4; ++j) {
            const int cidx = n0 + wn + 16 * j + lm;
            const float bv = bias ? bias[cidx] : 0.0f;
            const long rbase = m0 + wm + 16 * i + quad * 4;
#pragma unroll
            for (int r = 0; r < 4; ++r) {
                float v = alpha * acc[i][j][r] + addc + bv;
                const long row = rbase + r;
                const long off = row * (long)ldc + cidx;
                if (EP == 2) {
                    v += Cp[off];  // accumulate partial from plane pass 1
                    bf hi = __float2bfloat16(v);
                    bf lo = __float2bfloat16(v - __bfloat162float(hi));
                    if (cidx < 1024) {
                        qp[row * 2048 + cidx] = hi;
                        qp[row * 2048 + 1024 + cidx] = lo;
                    } else {
                        const int c = cidx - 1024;
                        kp[row * 2048 + 1024 + c] = hi;
                        kp[row * 2048 + c] = lo;
                    }
                } else if (EP == 1) {
                    Cbp[off] = __float2bfloat16(v);
                } else {
                    if (accumulate) v += Cp[off];
                    Cp[off] = v;
                }
            }
        }
    }
}

// ---------------------------------------------------------------------------
// Block reductions (256 threads = 4 waves of 64)
// ---------------------------------------------------------------------------
__device__ inline float blockReduceSum(float v, float* red)
{
#pragma unroll
    for (int off = 32; off > 0; off >>= 1) v += __shfl_xor(v, off, 64);
    __syncthreads();
    if ((threadIdx.x & 63) == 0) red[threadIdx.x >> 6] = v;
    __syncthreads();
    return red[0] + red[1] + red[2] + red[3];
}

__device__ inline float blockReduceMax(float v, float* red)
{
#pragma unroll
    for (int off = 32; off > 0; off >>= 1) v = fmaxf(v, __shfl_xor(v, off, 64));
    __syncthreads();
    if ((threadIdx.x & 63) == 0) red[threadIdx.x >> 6] = v;
    __syncthreads();
    return fmaxf(fmaxf(red[0], red[1]), fmaxf(red[2], red[3]));
}

__device__ inline void split_bf16(float v, bf& hi, bf& lo)
{
    hi = __float2bfloat16(v);
    lo = __float2bfloat16(v - __bfloat162float(hi));
}

// ---------------------------------------------------------------------------
// Weight prep (once per launch)
// ---------------------------------------------------------------------------
// Wqkv (2048x1024 fp32) -> Whihi (2048x2048: [hi|hi]) and Wlo (2048x1024)
__global__ __launch_bounds__(256) void prep_wqkv_kernel(
    const float* __restrict__ W, bf* __restrict__ whihi, bf* __restrict__ wlo)
{
    long i = (long)blockIdx.x * 256 + threadIdx.x;   // 2048*1024 threads
    long r = i >> 10; int c = (int)(i & 1023);
    bf hi, lo; split_bf16(W[i], hi, lo);
    whihi[r * 2048 + c] = hi;
    whihi[r * 2048 + 1024 + c] = hi;
    wlo[i] = lo;
}

// plain fp32 -> bf16 with source stride
__global__ __launch_bounds__(256) void conv_kernel(
    const float* __restrict__ src, bf* __restrict__ dst, int cols, int src_ld, long n)
{
    long i = (long)blockIdx.x * 256 + threadIdx.x;
    if (i >= n) return;
    long r = i / cols; int c = (int)(i % cols);
    dst[i] = __float2bfloat16(src[r * src_ld + c]);
}

// ---------------------------------------------------------------------------
// x -> xhl (S x 2048: [hi|lo]) and xT1 (D x S, bf16 hi). grid (32,32,G).
// ---------------------------------------------------------------------------
__global__ __launch_bounds__(256) void conv_x_kernel(
    const float* __restrict__ x, bf* __restrict__ xhl, bf* __restrict__ xT1)
{
    __shared__ float t[32][33];
    const int b = blockIdx.z;
    const int c0 = blockIdx.x * 32, r0 = blockIdx.y * 32;
    const int tx = threadIdx.x & 31, ty = threadIdx.x >> 5;  // ty 0..7
    const float* xb = x + (long)b * SS * DD;
    bf* xhlb = xhl + (long)b * SS * 2048;
#pragma unroll
    for (int p = 0; p < 4; ++p) {
        const int r = ty + 8 * p;
        const float v = xb[(long)(r0 + r) * DD + c0 + tx];
        t[r][tx] = v;
        bf hi, lo; split_bf16(v, hi, lo);
        xhlb[(long)(r0 + r) * 2048 + c0 + tx] = hi;
        xhlb[(long)(r0 + r) * 2048 + 1024 + c0 + tx] = lo;
    }
    __syncthreads();
#pragma unroll
    for (int p = 0; p < 4; ++p) {
        const int rr = ty + 8 * p;
        xT1[(long)b * DD * SS + (long)(c0 + rr) * SS + r0 + tx] =
            __float2bfloat16(t[tx][rr]);
    }
}

// ---------------------------------------------------------------------------
// L2-normalize each half-row (1024) of ctx fp32 (rows of 2048) -> bf16 out
// grid = nrows*2, block 256.
// ---------------------------------------------------------------------------
__global__ __launch_bounds__(256) void l2norm_conv_kernel(
    const float* __restrict__ ctx, bf* __restrict__ ctx_bf)
{
    __shared__ float red[4];
    const long row = blockIdx.x >> 1;
    const int half = blockIdx.x & 1;
    const float* p = ctx + row * 2048 + half * 1024;
    bf* q = ctx_bf + row * 2048 + half * 1024;
    const int t = threadIdx.x;

    float v[4];
    float ss = 0.0f;
#pragma unroll
    for (int i = 0; i < 4; ++i) { v[i] = p[t + 256 * i]; ss = fmaf(v[i], v[i], ss); }
    ss = blockReduceSum(ss, red);
    const float inv = 1.0f / fmaxf(sqrtf(ss), 1e-12f);
#pragma unroll
    for (int i = 0; i < 4; ++i) q[t + 256 * i] = __float2bfloat16(v[i] * inv);
}

// ---------------------------------------------------------------------------
// softmax -> mask -> L1 renorm, row 1024, fp32 in -> bf16 out. grid = nrows.
// ---------------------------------------------------------------------------
__global__ __launch_bounds__(256) void softmax_mask_kernel(
    const float* __restrict__ attn, const int* __restrict__ mask, bf* __restrict__ attn_bf)
{
    __shared__ float red[4];
    const long row = blockIdx.x;
    const float* p = attn + row * SS;
    const int* mrow = mask + row * SS;
    bf* o = attn_bf + row * SS;
    const int t = threadIdx.x;

    float v[4];
    int mv[4];
#pragma unroll
    for (int i = 0; i < 4; ++i) { v[i] = p[t + 256 * i]; mv[i] = mrow[t + 256 * i]; }
    float mx = fmaxf(fmaxf(v[0], v[1]), fmaxf(v[2], v[3]));
    mx = blockReduceMax(mx, red);

    float e[4];
    float s = 0.0f;
#pragma unroll
    for (int i = 0; i < 4; ++i) { e[i] = expf(v[i] - mx); s += e[i]; }
    s = blockReduceSum(s, red);

    float l1 = 0.0f;
#pragma unroll
    for (int i = 0; i < 4; ++i) { e[i] = mv[i] ? e[i] / s : 0.0f; l1 += e[i]; }
    l1 = blockReduceSum(l1, red);
    const float inv = 1.0f / fmaxf(l1, 1e-12f);
#pragma unroll
    for (int i = 0; i < 4; ++i) o[t + 256 * i] = __float2bfloat16(e[i] * inv);
}

// ---------------------------------------------------------------------------
extern "C" void kernel_launch(void* const* d_in, const int* in_sizes, int n_in,
                              void* d_out, int out_size, void* d_ws, size_t ws_size,
                              hipStream_t stream)
{
    const float* x    = (const float*)d_in[0];
    const int*   mask = (const int*)d_in[1];
    const float* Wqkv = (const float*)d_in[2];
    const float* bqkv = (const float*)d_in[3];
    const float* Wctx = (const float*)d_in[4];
    const float* bctx = (const float*)d_in[5];
    const float* Wf   = (const float*)d_in[6];
    const float* bfp  = (const float*)d_in[7];
    const float* Wo   = (const float*)d_in[8];
    const float* bo   = (const float*)d_in[9];
    float* out = (float*)d_out;

    const long SD = (long)SS * DD;                 // 1M elements per batch

    auto align_up = [](size_t v) { return (v + 255) & ~(size_t)255; };

    // Shared weight buffers
    const size_t sz_whihi = 2048L * 2048 * 2;      // 8.39 MB
    const size_t sz_wlo   = 2048L * 1024 * 2;      // 4.19 MB
    const size_t sz_wctx  = 2048L * 1024 * 2;      // 4.19 MB
    const size_t sz_wo    = 1024L * 1024 * 2;      // 2.1 MB
    const size_t SH = align_up(sz_whihi) + align_up(sz_wlo) + align_up(sz_wctx) +
                      2 * align_up(sz_wo);

    // Per-batch pooled regions:
    //   R1 (8.39 MB): qkvf fp32 -> ctxf fp32 -> {attnb, valb}
    //   R2 (4.19 MB): Qbuf -> ctxb
    //   R3 (4.19 MB): Kbuf -> Y1
    //   R4 (4.19 MB): attn fp32
    //   R5 (4.19 MB): xhl
    //   R6 (2.10 MB): xT1
    const size_t szR1 = 1024L * 2048 * 4;
    const size_t szR2 = 1024L * 2048 * 2;
    const size_t szR3 = 1024L * 2048 * 2;
    const size_t szR4 = 1024L * 1024 * 4;
    const size_t szR5 = 1024L * 2048 * 2;
    const size_t szR6 = 1024L * 1024 * 2;
    const size_t PB = align_up(szR1) + align_up(szR2) + align_up(szR3) +
                      align_up(szR4) + align_up(szR5) + align_up(szR6);

    int G = 16;
    while (G > 1 && SH + (size_t)G * PB > ws_size) G >>= 1;

    char* p = (char*)d_ws;
    auto take = [&](size_t bytes) { char* r = p; p += align_up(bytes); return r; };
    bf* Whihi = (bf*)take(sz_whihi);
    bf* Wlo   = (bf*)take(sz_wlo);
    bf* Wctx1 = (bf*)take(sz_wctx);
    bf* Wo1b  = (bf*)take(sz_wo);
    bf* Wo2b  = (bf*)take(sz_wo);
    char* R1 = take((size_t)G * szR1);
    char* R2 = take((size_t)G * szR2);
    char* R3 = take((size_t)G * szR3);
    char* R4 = take((size_t)G * szR4);
    char* R5 = take((size_t)G * szR5);
    char* R6 = take((size_t)G * szR6);

    float* qkvf = (float*)R1;                        // G x (1024 x 2048) fp32
    float* ctxf = (float*)R1;                        // G x (1024 x 2048) fp32
    bf* attnb   = (bf*)R1;                           // G x (1024 x 1024) bf16
    bf* valb    = (bf*)(R1 + (size_t)G * 1024 * 1024 * 2);
    bf* Qbuf = (bf*)R2;                              // G x (1024 x 2048) [hi|lo]
    bf* ctxb = (bf*)R2;
    bf* Kbuf = (bf*)R3;                              // G x (1024 x 2048) [lo|hi]
    bf* Y1   = (bf*)R3;                              // G x (2048 x 1024)
    float* attn = (float*)R4;                        // G x (1024 x 1024) fp32
    bf* xhl = (bf*)R5;                               // G x (1024 x 2048) [hi|lo]
    bf* xT1 = (bf*)R6;                               // G x (1024 x 1024)

    const dim3 blk(256);
    const long sQ = 1024L * 2048;                    // per-batch stride, Q/K/xhl/ctx
    const long sAT = 1024L * 1024;

    // --- weight prep (once) ---
    prep_wqkv_kernel<<<dim3((2048L * 1024) / 256), blk, 0, stream>>>(Wqkv, Whihi, Wlo);
    conv_kernel<<<dim3((2048L * 1024) / 256), blk, 0, stream>>>(Wctx, Wctx1, 1024, 1024, 2048L * 1024);
    conv_kernel<<<dim3((1024L * 1024) / 256), blk, 0, stream>>>(Wo, Wo1b, 1024, 2048, 1024L * 1024);
    conv_kernel<<<dim3((1024L * 1024) / 256), blk, 0, stream>>>(Wo + 1024, Wo2b, 1024, 2048, 1024L * 1024);

    for (int bc0 = 0; bc0 < BB; bc0 += G) {
        const float* xb = x + (long)bc0 * SD;
        const int M = G * 1024;                      // flattened rows this chunk

        // 0. x -> xhl, xT1
        conv_x_kernel<<<dim3(32, 32, G), blk, 0, stream>>>(xb, xhl, xT1);

        // 1a. qkvf = [xhi|xlo] * [Whi|Whi]^T + bqkv   (K=2048, flattened M)
        gemm_bf16_nt<0><<<dim3(16, M / 128), blk, 0, stream>>>(
            xhl, 0, 2048, Whihi, 0, 2048,
            qkvf, nullptr, nullptr, nullptr, 0, 2048, 2048,
            bqkv, nullptr, 0, nullptr, 0);

        // 1b. qkvf += xhi * Wlo^T; split-write Qbuf ([hi|lo]) / Kbuf ([lo|hi])
        gemm_bf16_nt<2><<<dim3(16, M / 128), blk, 0, stream>>>(
            xhl, 0, 2048, Wlo, 0, 1024,
            qkvf, nullptr, Qbuf, Kbuf, 0, 2048, 1024,
            nullptr, nullptr, 0, nullptr, 1);

        // 2a. attn = Wf0 * (Qhi Khi^T) + bf          (K=1024, per batch)
        gemm_bf16_nt<0><<<dim3(8, 8, G), blk, 0, stream>>>(
            Qbuf, sQ, 2048, Kbuf + 1024, sQ, 2048,
            attn, nullptr, nullptr, nullptr, sAT, 1024, 1024,
            nullptr, Wf, 0, bfp, 0);

        // 2b. attn += Wf0 * (Q [Klo|Khi]^T)          (K=2048: qhi*klo + qlo*khi)
        gemm_bf16_nt<0><<<dim3(8, 8, G), blk, 0, stream>>>(
            Qbuf, sQ, 2048, Kbuf, sQ, 2048,
            attn, nullptr, nullptr, nullptr, sAT, 1024, 2048,
            nullptr, Wf, 0, nullptr, 1);

        // 3. Y1 = Wctx * x^T  (NT via xT1), bf16 out (per batch)
        gemm_bf16_nt<1><<<dim3(8, 16, G), blk, 0, stream>>>(
            Wctx1, 0, 1024, xT1, sAT, 1024,
            nullptr, Y1, nullptr, nullptr, sQ, 1024, 1024,
            nullptr, nullptr, 0, nullptr, 0);

        // 4. ctxf = xhi * Y1^T + bctx                (per batch)
        gemm_bf16_nt<0><<<dim3(16, 8, G), blk, 0, stream>>>(
            xhl, sQ, 2048, Y1, sQ, 1024,
            ctxf, nullptr, nullptr, nullptr, sQ, 2048, 1024,
            bctx, nullptr, 0, nullptr, 0);

        // 5. L2-normalize halves -> ctxb
        l2norm_conv_kernel<<<dim3(G * 1024 * 2), blk, 0, stream>>>(ctxf, ctxb);

        // 6. attn += Wf1 * ctx_q ctx_k^T
        gemm_bf16_nt<0><<<dim3(8, 8, G), blk, 0, stream>>>(
            ctxb, sQ, 2048, ctxb + 1024, sQ, 2048,
            attn, nullptr, nullptr, nullptr, sAT, 1024, 1024,
            nullptr, Wf, 1, nullptr, 1);

        // 7. softmax -> mask -> L1 renorm -> attnb
        softmax_mask_kernel<<<dim3(G * 1024), blk, 0, stream>>>(
            attn, mask + (long)bc0 * SS * SS, attnb);

        // 8. valb = attnb * x^T (NT via xT1), bf16 out (per batch)
        gemm_bf16_nt<1><<<dim3(8, 8, G), blk, 0, stream>>>(
            attnb, sAT, 1024, xT1, sAT, 1024,
            nullptr, valb, nullptr, nullptr, sAT, 1024, 1024,
            nullptr, nullptr, 0, nullptr, 0);

        // 9. out = xhi * Wo1^T + bo                  (flattened M)
        gemm_bf16_nt<0><<<dim3(8, M / 128), blk, 0, stream>>>(
            xhl, 0, 2048, Wo1b, 0, 1024,
            out + (long)bc0 * SD, nullptr, nullptr, nullptr, 0, 1024, 1024,
            bo, nullptr, 0, nullptr, 0);

        // 10. out += valb * Wo2^T                    (flattened M)
        gemm_bf16_nt<0><<<dim3(8, M / 128), blk, 0, stream>>>(
            valb, 0, 1024, Wo2b, 0, 1024,
            out + (long)bc0 * SD, nullptr, nullptr, nullptr, 0, 1024, 1024,
            nullptr, nullptr, 0, nullptr, 1);
    }
}